// Round 1
// baseline (986.202 us; speedup 1.0000x reference)
//
#include <hip/hip_runtime.h>
#include <hip/hip_bf16.h>
#include <math.h>

// Problem constants (LongcatMoe): T tokens, H hidden, I intermediate,
// E routed experts, Z zero experts, top-4 routing, routed_scaling = 1.0
constexpr int T   = 1024;
constexpr int H   = 2048;
constexpr int I   = 1024;
constexpr int E   = 8;
constexpr int NEZ = 16;   // E + Z
constexpr int TK  = 4;    // TOP_K

// ---------------------------------------------------------------------------
// Router: logits = x @ rw^T (16 experts), softmax, +bias for selection only,
// top-4 (first-index tie-break like lax.top_k). Builds per-expert compacted
// token lists (entry = (t<<2)|slot), per-slot combine weights wk4[t][k]
// (0 for zero-experts), and zero-expert weight zerow[t].
// ---------------------------------------------------------------------------
__global__ __launch_bounds__(256) void router_kernel(
    const float* __restrict__ x, const float* __restrict__ rw,
    const float* __restrict__ bias, int* __restrict__ cnt,
    int* __restrict__ list, float* __restrict__ wk4,
    float* __restrict__ zerow)
{
  const int t   = blockIdx.x;
  const int tid = threadIdx.x;
  const float* xt = x + (size_t)t * H;

  float acc[NEZ];
#pragma unroll
  for (int e = 0; e < NEZ; e++) acc[e] = 0.f;

  for (int h = tid; h < H; h += 256) {
    const float xv = xt[h];
#pragma unroll
    for (int e = 0; e < NEZ; e++) acc[e] = fmaf(xv, rw[e * H + h], acc[e]);
  }

  // wave64 butterfly reduce each accumulator
#pragma unroll
  for (int e = 0; e < NEZ; e++) {
    float v = acc[e];
#pragma unroll
    for (int off = 32; off >= 1; off >>= 1) v += __shfl_down(v, off, 64);
    acc[e] = v;
  }

  __shared__ float red[4][NEZ];
  const int wv = tid >> 6, ln = tid & 63;
  if (ln == 0) {
#pragma unroll
    for (int e = 0; e < NEZ; e++) red[wv][e] = acc[e];
  }
  __syncthreads();

  if (tid == 0) {
    float l[NEZ];
    float mx = -1e30f;
#pragma unroll
    for (int e = 0; e < NEZ; e++) {
      l[e] = red[0][e] + red[1][e] + red[2][e] + red[3][e];
      mx = fmaxf(mx, l[e]);
    }
    float s = 0.f;
#pragma unroll
    for (int e = 0; e < NEZ; e++) { l[e] = expf(l[e] - mx); s += l[e]; }
    const float inv = 1.f / s;
    float sc[NEZ], sel[NEZ];
#pragma unroll
    for (int e = 0; e < NEZ; e++) {
      sc[e]  = l[e] * inv;
      sel[e] = sc[e] + bias[e];
    }
    float zw = 0.f;
#pragma unroll
    for (int k = 0; k < TK; k++) {
      int best = 0; float bv = sel[0];
#pragma unroll
      for (int e = 1; e < NEZ; e++) {
        if (sel[e] > bv) { bv = sel[e]; best = e; }   // strict > == first-index tie-break
      }
      sel[best] = -1e30f;
      const float w = sc[best];  // gating weight from pre-bias scores; scaling = 1.0
      if (best < E) {
        const int pos = atomicAdd(&cnt[best], 1);
        list[best * T + pos] = (t << 2) | k;
        wk4[t * TK + k] = w;
      } else {
        wk4[t * TK + k] = 0.f;
        zw += w;
      }
    }
    zerow[t] = zw;
  }
}

// ---------------------------------------------------------------------------
// Grouped gate+up GEMM per expert, fused silu(gate)*up -> mid buffer.
// C[M x I] tile 64x64, K = H, K-step 16. A rows gathered via token list.
// As stored transposed [k][m] with +4 pad (16B-aligned rows, 2-way-max bank
// aliasing on the strided writes, conflict-free float4 reads).
// ---------------------------------------------------------------------------
__global__ __launch_bounds__(256) void gateup_kernel(
    const float* __restrict__ x, const float* __restrict__ wg,
    const float* __restrict__ wu, const int* __restrict__ cnt,
    const int* __restrict__ list, float* __restrict__ midb)
{
  const int e  = blockIdx.z;
  const int m0 = blockIdx.x * 64;
  const int n0 = blockIdx.y * 64;
  const int ce = cnt[e];
  if (m0 >= ce) return;

  __shared__ __align__(16) float As[16][68];
  __shared__ __align__(16) float Bg[16][64];
  __shared__ __align__(16) float Bu[16][64];

  const int tid = threadIdx.x;
  const int tx  = tid & 15;   // output col group (4 cols)
  const int ty  = tid >> 4;   // output row group (4 rows)

  const int lrow = tid >> 2;        // A loader: row 0..63
  const int lk4  = (tid & 3) * 4;   // A loader: k offset 0/4/8/12
  const int brow = tid >> 4;        // B loader: k row 0..15
  const int bc4  = (tid & 15) * 4;  // B loader: col offset

  int tokr = 0;
  if (m0 + lrow < ce) tokr = list[e * T + m0 + lrow] >> 2;
  const float* xrow = x + (size_t)tokr * H;

  const float* wge = wg + (size_t)e * H * I;
  const float* wue = wu + (size_t)e * H * I;

  float accg[4][4] = {};
  float accu[4][4] = {};

  for (int k0 = 0; k0 < H; k0 += 16) {
    const float4 av = *(const float4*)(xrow + k0 + lk4);
    As[lk4 + 0][lrow] = av.x;
    As[lk4 + 1][lrow] = av.y;
    As[lk4 + 2][lrow] = av.z;
    As[lk4 + 3][lrow] = av.w;
    *(float4*)&Bg[brow][bc4] =
        *(const float4*)(wge + (size_t)(k0 + brow) * I + n0 + bc4);
    *(float4*)&Bu[brow][bc4] =
        *(const float4*)(wue + (size_t)(k0 + brow) * I + n0 + bc4);
    __syncthreads();
#pragma unroll
    for (int kk = 0; kk < 16; kk++) {
      const float4 a  = *(const float4*)&As[kk][ty * 4];
      const float4 bg = *(const float4*)&Bg[kk][tx * 4];
      const float4 bu = *(const float4*)&Bu[kk][tx * 4];
      const float am[4]  = {a.x, a.y, a.z, a.w};
      const float bgm[4] = {bg.x, bg.y, bg.z, bg.w};
      const float bum[4] = {bu.x, bu.y, bu.z, bu.w};
#pragma unroll
      for (int i = 0; i < 4; i++) {
#pragma unroll
        for (int j = 0; j < 4; j++) {
          accg[i][j] = fmaf(am[i], bgm[j], accg[i][j]);
          accu[i][j] = fmaf(am[i], bum[j], accu[i][j]);
        }
      }
    }
    __syncthreads();
  }

#pragma unroll
  for (int i = 0; i < 4; i++) {
    const int r = m0 + ty * 4 + i;
    if (r >= ce) continue;
    float* mrow = midb + ((size_t)e * T + r) * I + n0;
#pragma unroll
    for (int j = 0; j < 4; j++) {
      const float g = accg[i][j];
      const float u = accu[i][j];
      const float sg = g / (1.f + expf(-g));  // silu
      mrow[tx * 4 + j] = sg * u;
    }
  }
}

// ---------------------------------------------------------------------------
// Grouped down GEMM per expert: down[(t,slot)][H] = mid[row] @ w_down[e].
// K = I, tile 64x64.
// ---------------------------------------------------------------------------
__global__ __launch_bounds__(256) void down_kernel(
    const float* __restrict__ midb, const float* __restrict__ wd,
    const int* __restrict__ cnt, const int* __restrict__ list,
    float* __restrict__ downb)
{
  const int e  = blockIdx.z;
  const int m0 = blockIdx.x * 64;
  const int n0 = blockIdx.y * 64;
  const int ce = cnt[e];
  if (m0 >= ce) return;

  __shared__ __align__(16) float As[16][68];
  __shared__ __align__(16) float Bd[16][64];

  const int tid = threadIdx.x;
  const int tx  = tid & 15;
  const int ty  = tid >> 4;

  const int lrow = tid >> 2;
  const int lk4  = (tid & 3) * 4;
  const int brow = tid >> 4;
  const int bc4  = (tid & 15) * 4;

  const int arow_idx = (m0 + lrow < ce) ? (m0 + lrow) : (ce - 1);
  const float* arow = midb + ((size_t)e * T + arow_idx) * I;
  const float* wde  = wd + (size_t)e * I * H;

  float acc[4][4] = {};

  for (int k0 = 0; k0 < I; k0 += 16) {
    const float4 av = *(const float4*)(arow + k0 + lk4);
    As[lk4 + 0][lrow] = av.x;
    As[lk4 + 1][lrow] = av.y;
    As[lk4 + 2][lrow] = av.z;
    As[lk4 + 3][lrow] = av.w;
    *(float4*)&Bd[brow][bc4] =
        *(const float4*)(wde + (size_t)(k0 + brow) * H + n0 + bc4);
    __syncthreads();
#pragma unroll
    for (int kk = 0; kk < 16; kk++) {
      const float4 a = *(const float4*)&As[kk][ty * 4];
      const float4 b = *(const float4*)&Bd[kk][tx * 4];
      const float am[4] = {a.x, a.y, a.z, a.w};
      const float bm[4] = {b.x, b.y, b.z, b.w};
#pragma unroll
      for (int i = 0; i < 4; i++) {
#pragma unroll
        for (int j = 0; j < 4; j++) {
          acc[i][j] = fmaf(am[i], bm[j], acc[i][j]);
        }
      }
    }
    __syncthreads();
  }

#pragma unroll
  for (int i = 0; i < 4; i++) {
    const int r = m0 + ty * 4 + i;
    if (r >= ce) continue;
    const int ent  = list[e * T + r];
    const int tok  = ent >> 2;
    const int slot = ent & 3;
    float* drow = downb + ((size_t)tok * TK + slot) * H + n0;
#pragma unroll
    for (int j = 0; j < 4; j++) drow[tx * 4 + j] = acc[i][j];
  }
}

// ---------------------------------------------------------------------------
// Combine: out[t][h] = sum_k wk4[t][k] * down[(t,k)][h] + zerow[t] * x[t][h]
// wk4 is 0 for zero-expert slots, so stale down_buf contents are harmless.
// ---------------------------------------------------------------------------
__global__ __launch_bounds__(256) void combine_kernel(
    const float* __restrict__ x, const float* __restrict__ downb,
    const float* __restrict__ wk4, const float* __restrict__ zerow,
    float* __restrict__ out)
{
  const int idx = blockIdx.x * 256 + threadIdx.x;  // float4 index
  const int t   = idx >> 9;           // H/4 = 512 float4 per row
  const int h   = (idx & 511) * 4;

  const float w0 = wk4[t * TK + 0];
  const float w1 = wk4[t * TK + 1];
  const float w2 = wk4[t * TK + 2];
  const float w3 = wk4[t * TK + 3];
  const float zw = zerow[t];

  const float4 xv = *(const float4*)(x + (size_t)t * H + h);
  const float4 d0 = *(const float4*)(downb + ((size_t)t * TK + 0) * H + h);
  const float4 d1 = *(const float4*)(downb + ((size_t)t * TK + 1) * H + h);
  const float4 d2 = *(const float4*)(downb + ((size_t)t * TK + 2) * H + h);
  const float4 d3 = *(const float4*)(downb + ((size_t)t * TK + 3) * H + h);

  float4 o;
  o.x = w0 * d0.x + w1 * d1.x + w2 * d2.x + w3 * d3.x + zw * xv.x;
  o.y = w0 * d0.y + w1 * d1.y + w2 * d2.y + w3 * d3.y + zw * xv.y;
  o.z = w0 * d0.z + w1 * d1.z + w2 * d2.z + w3 * d3.z + zw * xv.z;
  o.w = w0 * d0.w + w1 * d1.w + w2 * d2.w + w3 * d3.w + zw * xv.w;
  *(float4*)(out + (size_t)t * H + h) = o;
}

// ---------------------------------------------------------------------------
extern "C" void kernel_launch(void* const* d_in, const int* in_sizes, int n_in,
                              void* d_out, int out_size, void* d_ws, size_t ws_size,
                              hipStream_t stream) {
  const float* x    = (const float*)d_in[0];  // [T, H]
  const float* rw   = (const float*)d_in[1];  // [E+Z, H]
  const float* bias = (const float*)d_in[2];  // [E+Z]
  const float* wg   = (const float*)d_in[3];  // [E, H, I]
  const float* wu   = (const float*)d_in[4];  // [E, H, I]
  const float* wd   = (const float*)d_in[5];  // [E, I, H]
  float* out = (float*)d_out;

  // workspace layout
  char* ws = (char*)d_ws;
  size_t off = 0;
  auto alloc = [&](size_t bytes) {
    void* p = ws + off;
    off = (off + bytes + 255) & ~(size_t)255;
    return p;
  };
  int*   cnt   = (int*)  alloc(E * sizeof(int));
  int*   list  = (int*)  alloc((size_t)E * T * sizeof(int));
  float* wk4   = (float*)alloc((size_t)T * TK * sizeof(float));
  float* zerow = (float*)alloc((size_t)T * sizeof(float));
  float* midb  = (float*)alloc((size_t)E * T * I * sizeof(float));   // 32 MB
  float* downb = (float*)alloc((size_t)T * TK * H * sizeof(float));  // 32 MB
  (void)ws_size;

  hipMemsetAsync(cnt, 0, E * sizeof(int), stream);

  router_kernel<<<T, 256, 0, stream>>>(x, rw, bias, cnt, list, wk4, zerow);

  gateup_kernel<<<dim3(T / 64, I / 64, E), 256, 0, stream>>>(
      x, wg, wu, cnt, list, midb);

  down_kernel<<<dim3(T / 64, H / 64, E), 256, 0, stream>>>(
      midb, wd, cnt, list, downb);

  combine_kernel<<<(T * H / 4) / 256, 256, 0, stream>>>(
      x, downb, wk4, zerow, out);
}

// Round 2
// 510.421 us; speedup vs baseline: 1.9321x; 1.9321x over previous
//
#include <hip/hip_runtime.h>
#include <hip/hip_bf16.h>
#include <math.h>

constexpr int T   = 1024;
constexpr int H   = 2048;
constexpr int I   = 1024;
constexpr int E   = 8;
constexpr int NEZ = 16;   // E + Z
constexpr int TK  = 4;    // TOP_K

typedef short bf16x8 __attribute__((ext_vector_type(8)));
typedef float f32x4  __attribute__((ext_vector_type(4)));
typedef unsigned short u16;
typedef u16 u16x8 __attribute__((ext_vector_type(8)));

__device__ inline u16 bf16rn(float x) {
  unsigned u = __builtin_bit_cast(unsigned, x);
  u = u + 0x7FFFu + ((u >> 16) & 1u);
  return (u16)(u >> 16);
}
__device__ inline float bf16tof(u16 h) {
  return __builtin_bit_cast(float, (unsigned)h << 16);
}

// ---------------------------------------------------------------------------
// Router: unchanged from round 1 (passed; not the bottleneck).
// ---------------------------------------------------------------------------
__global__ __launch_bounds__(256) void router_kernel(
    const float* __restrict__ x, const float* __restrict__ rw,
    const float* __restrict__ bias, int* __restrict__ cnt,
    int* __restrict__ list, float* __restrict__ wk4,
    float* __restrict__ zerow)
{
  const int t   = blockIdx.x;
  const int tid = threadIdx.x;
  const float* xt = x + (size_t)t * H;

  float acc[NEZ];
#pragma unroll
  for (int e = 0; e < NEZ; e++) acc[e] = 0.f;

  for (int h = tid; h < H; h += 256) {
    const float xv = xt[h];
#pragma unroll
    for (int e = 0; e < NEZ; e++) acc[e] = fmaf(xv, rw[e * H + h], acc[e]);
  }

#pragma unroll
  for (int e = 0; e < NEZ; e++) {
    float v = acc[e];
#pragma unroll
    for (int off = 32; off >= 1; off >>= 1) v += __shfl_down(v, off, 64);
    acc[e] = v;
  }

  __shared__ float red[4][NEZ];
  const int wv = tid >> 6, ln = tid & 63;
  if (ln == 0) {
#pragma unroll
    for (int e = 0; e < NEZ; e++) red[wv][e] = acc[e];
  }
  __syncthreads();

  if (tid == 0) {
    float l[NEZ];
    float mx = -1e30f;
#pragma unroll
    for (int e = 0; e < NEZ; e++) {
      l[e] = red[0][e] + red[1][e] + red[2][e] + red[3][e];
      mx = fmaxf(mx, l[e]);
    }
    float s = 0.f;
#pragma unroll
    for (int e = 0; e < NEZ; e++) { l[e] = expf(l[e] - mx); s += l[e]; }
    const float inv = 1.f / s;
    float sc[NEZ], sel[NEZ];
#pragma unroll
    for (int e = 0; e < NEZ; e++) {
      sc[e]  = l[e] * inv;
      sel[e] = sc[e] + bias[e];
    }
    float zw = 0.f;
#pragma unroll
    for (int k = 0; k < TK; k++) {
      int best = 0; float bv = sel[0];
#pragma unroll
      for (int e = 1; e < NEZ; e++) {
        if (sel[e] > bv) { bv = sel[e]; best = e; }
      }
      sel[best] = -1e30f;
      const float w = sc[best];
      if (best < E) {
        const int pos = atomicAdd(&cnt[best], 1);
        list[best * T + pos] = (t << 2) | k;
        wk4[t * TK + k] = w;
      } else {
        wk4[t * TK + k] = 0.f;
        zw += w;
      }
    }
    zerow[t] = zw;
  }
}

// ---------------------------------------------------------------------------
// Gate+Up grouped GEMM, bf16 hi/lo 3-term MFMA emulation of fp32.
// Tile 128x128, BK=32 (fp32 k-elems), 4 waves (2x2 of 64x64).
// A = gathered x rows (k-contiguous). B = weights [H][I] (k-major) ->
// transposed+converted into LDS [BN][BK+8] during staging.
// Output: silu(gate)*up split into bf16 hi/lo buffers.
// ---------------------------------------------------------------------------
__global__ __launch_bounds__(256, 2) void gateup_kernel(
    const float* __restrict__ x, const float* __restrict__ wg,
    const float* __restrict__ wu, const int* __restrict__ cnt,
    const int* __restrict__ list,
    u16* __restrict__ mid_hi, u16* __restrict__ mid_lo)
{
  const int e  = blockIdx.z;
  const int m0 = blockIdx.x * 128;
  const int n0 = blockIdx.y * 128;
  const int ce = cnt[e];
  if (m0 >= ce) return;

  __shared__ short Ah[128][40], Al[128][40];
  __shared__ short Bgh[128][40], Bgl[128][40];
  __shared__ short Buh[128][40], Bul[128][40];

  const int tid = threadIdx.x;

  // A staging: 2 threads per row, 16 k each
  const int arow = tid >> 1;
  const int akq  = (tid & 1) * 16;
  int tok = 0;
  if (m0 + arow < ce) tok = list[e * T + m0 + arow] >> 2;
  const float* xrow = x + (size_t)tok * H;

  // B staging: thread -> k-quad (bkq*4..+3) x 4 n's (bnl + 32j)
  const int bkq = tid >> 5;   // 0..7
  const int bnl = tid & 31;
  const float* wge = wg + (size_t)e * H * I;
  const float* wue = wu + (size_t)e * H * I;

  const int lane = tid & 63;
  const int w    = tid >> 6;
  const int wm   = w >> 1, wn = w & 1;
  const int l15  = lane & 15, lg = lane >> 4;

  f32x4 accg[4][4] = {};
  f32x4 accu[4][4] = {};

  for (int k0 = 0; k0 < H; k0 += 32) {
    // ---- stage A ----
    {
      const float* p = xrow + k0 + akq;
      float v[16];
      *(float4*)&v[0]  = *(const float4*)(p);
      *(float4*)&v[4]  = *(const float4*)(p + 4);
      *(float4*)&v[8]  = *(const float4*)(p + 8);
      *(float4*)&v[12] = *(const float4*)(p + 12);
      u16x8 h0, h1, l0, l1;
#pragma unroll
      for (int i = 0; i < 8; i++) {
        u16 hh = bf16rn(v[i]);
        h0[i] = hh; l0[i] = bf16rn(v[i] - bf16tof(hh));
      }
#pragma unroll
      for (int i = 0; i < 8; i++) {
        u16 hh = bf16rn(v[8 + i]);
        h1[i] = hh; l1[i] = bf16rn(v[8 + i] - bf16tof(hh));
      }
      *(u16x8*)&Ah[arow][akq]     = h0;
      *(u16x8*)&Ah[arow][akq + 8] = h1;
      *(u16x8*)&Al[arow][akq]     = l0;
      *(u16x8*)&Al[arow][akq + 8] = l1;
    }
    // ---- stage B (transpose + convert) ----
#pragma unroll
    for (int j = 0; j < 4; j++) {
      const int n = bnl + j * 32;
      const size_t col = (size_t)(n0 + n);
      const size_t rb  = (size_t)(k0 + bkq * 4) * I + col;
      {
        float g0 = wge[rb], g1 = wge[rb + I], g2 = wge[rb + 2 * I], g3 = wge[rb + 3 * I];
        u16 h0 = bf16rn(g0), h1 = bf16rn(g1), h2 = bf16rn(g2), h3 = bf16rn(g3);
        u16 q0 = bf16rn(g0 - bf16tof(h0)), q1 = bf16rn(g1 - bf16tof(h1));
        u16 q2 = bf16rn(g2 - bf16tof(h2)), q3 = bf16rn(g3 - bf16tof(h3));
        uint2 ph = {(unsigned)h0 | ((unsigned)h1 << 16), (unsigned)h2 | ((unsigned)h3 << 16)};
        uint2 pl = {(unsigned)q0 | ((unsigned)q1 << 16), (unsigned)q2 | ((unsigned)q3 << 16)};
        *(uint2*)&Bgh[n][bkq * 4] = ph;
        *(uint2*)&Bgl[n][bkq * 4] = pl;
      }
      {
        float g0 = wue[rb], g1 = wue[rb + I], g2 = wue[rb + 2 * I], g3 = wue[rb + 3 * I];
        u16 h0 = bf16rn(g0), h1 = bf16rn(g1), h2 = bf16rn(g2), h3 = bf16rn(g3);
        u16 q0 = bf16rn(g0 - bf16tof(h0)), q1 = bf16rn(g1 - bf16tof(h1));
        u16 q2 = bf16rn(g2 - bf16tof(h2)), q3 = bf16rn(g3 - bf16tof(h3));
        uint2 ph = {(unsigned)h0 | ((unsigned)h1 << 16), (unsigned)h2 | ((unsigned)h3 << 16)};
        uint2 pl = {(unsigned)q0 | ((unsigned)q1 << 16), (unsigned)q2 | ((unsigned)q3 << 16)};
        *(uint2*)&Buh[n][bkq * 4] = ph;
        *(uint2*)&Bul[n][bkq * 4] = pl;
      }
    }
    __syncthreads();

    // ---- compute ----
    bf16x8 ah[4], al[4];
#pragma unroll
    for (int mi = 0; mi < 4; mi++) {
      const int r = wm * 64 + mi * 16 + l15;
      ah[mi] = *(const bf16x8*)&Ah[r][lg * 8];
      al[mi] = *(const bf16x8*)&Al[r][lg * 8];
    }
#pragma unroll
    for (int ni = 0; ni < 4; ni++) {
      const int n = wn * 64 + ni * 16 + l15;
      const bf16x8 bgh = *(const bf16x8*)&Bgh[n][lg * 8];
      const bf16x8 bgl = *(const bf16x8*)&Bgl[n][lg * 8];
      const bf16x8 buh = *(const bf16x8*)&Buh[n][lg * 8];
      const bf16x8 bul = *(const bf16x8*)&Bul[n][lg * 8];
#pragma unroll
      for (int mi = 0; mi < 4; mi++) {
        accg[mi][ni] = __builtin_amdgcn_mfma_f32_16x16x32_bf16(ah[mi], bgh, accg[mi][ni], 0, 0, 0);
        accg[mi][ni] = __builtin_amdgcn_mfma_f32_16x16x32_bf16(ah[mi], bgl, accg[mi][ni], 0, 0, 0);
        accg[mi][ni] = __builtin_amdgcn_mfma_f32_16x16x32_bf16(al[mi], bgh, accg[mi][ni], 0, 0, 0);
        accu[mi][ni] = __builtin_amdgcn_mfma_f32_16x16x32_bf16(ah[mi], buh, accu[mi][ni], 0, 0, 0);
        accu[mi][ni] = __builtin_amdgcn_mfma_f32_16x16x32_bf16(ah[mi], bul, accu[mi][ni], 0, 0, 0);
        accu[mi][ni] = __builtin_amdgcn_mfma_f32_16x16x32_bf16(al[mi], buh, accu[mi][ni], 0, 0, 0);
      }
    }
    __syncthreads();
  }

  // ---- epilogue: silu(g)*u, split to bf16 hi/lo ----
#pragma unroll
  for (int mi = 0; mi < 4; mi++) {
#pragma unroll
    for (int rr = 0; rr < 4; rr++) {
      const int m = m0 + wm * 64 + mi * 16 + lg * 4 + rr;
      if (m >= ce) continue;
      const size_t rowoff = ((size_t)e * T + m) * I;
#pragma unroll
      for (int ni = 0; ni < 4; ni++) {
        const int n = n0 + wn * 64 + ni * 16 + l15;
        const float g = accg[mi][ni][rr];
        const float u = accu[mi][ni][rr];
        const float mid = (g / (1.f + expf(-g))) * u;
        const u16 h = bf16rn(mid);
        const u16 l = bf16rn(mid - bf16tof(h));
        mid_hi[rowoff + n] = h;
        mid_lo[rowoff + n] = l;
      }
    }
  }
}

// ---------------------------------------------------------------------------
// Down grouped GEMM: mid (already bf16 hi/lo) @ w_down[e] ([I][H] fp32).
// Same tile structure; single output matrix (48 MFMA/K-step/wave).
// ---------------------------------------------------------------------------
__global__ __launch_bounds__(256, 2) void down_kernel(
    const u16* __restrict__ mid_hi, const u16* __restrict__ mid_lo,
    const float* __restrict__ wd, const int* __restrict__ cnt,
    const int* __restrict__ list, float* __restrict__ downb)
{
  const int e  = blockIdx.z;
  const int m0 = blockIdx.x * 128;
  const int n0 = blockIdx.y * 128;
  const int ce = cnt[e];
  if (m0 >= ce) return;

  __shared__ short Ah[128][40], Al[128][40];
  __shared__ short Bh[128][40], Bl[128][40];

  const int tid = threadIdx.x;

  const int arow = tid >> 1;
  const int akq  = (tid & 1) * 16;
  const int amr  = (m0 + arow < ce) ? (m0 + arow) : (ce - 1);
  const u16* mhrow = mid_hi + ((size_t)e * T + amr) * I;
  const u16* mlrow = mid_lo + ((size_t)e * T + amr) * I;

  const int bkq = tid >> 5;
  const int bnl = tid & 31;
  const float* wde = wd + (size_t)e * I * H;

  const int lane = tid & 63;
  const int w    = tid >> 6;
  const int wm   = w >> 1, wn = w & 1;
  const int l15  = lane & 15, lg = lane >> 4;

  f32x4 acc[4][4] = {};

  for (int k0 = 0; k0 < I; k0 += 32) {
    // ---- stage A (already bf16 pairs: pure copy) ----
    {
      const u16x8 a0 = *(const u16x8*)(mhrow + k0 + akq);
      const u16x8 a1 = *(const u16x8*)(mhrow + k0 + akq + 8);
      const u16x8 b0 = *(const u16x8*)(mlrow + k0 + akq);
      const u16x8 b1 = *(const u16x8*)(mlrow + k0 + akq + 8);
      *(u16x8*)&Ah[arow][akq]     = a0;
      *(u16x8*)&Ah[arow][akq + 8] = a1;
      *(u16x8*)&Al[arow][akq]     = b0;
      *(u16x8*)&Al[arow][akq + 8] = b1;
    }
    // ---- stage B (transpose + convert) ----
#pragma unroll
    for (int j = 0; j < 4; j++) {
      const int n = bnl + j * 32;
      const size_t rb = (size_t)(k0 + bkq * 4) * H + (size_t)(n0 + n);
      float g0 = wde[rb], g1 = wde[rb + H], g2 = wde[rb + 2 * H], g3 = wde[rb + 3 * H];
      u16 h0 = bf16rn(g0), h1 = bf16rn(g1), h2 = bf16rn(g2), h3 = bf16rn(g3);
      u16 q0 = bf16rn(g0 - bf16tof(h0)), q1 = bf16rn(g1 - bf16tof(h1));
      u16 q2 = bf16rn(g2 - bf16tof(h2)), q3 = bf16rn(g3 - bf16tof(h3));
      uint2 ph = {(unsigned)h0 | ((unsigned)h1 << 16), (unsigned)h2 | ((unsigned)h3 << 16)};
      uint2 pl = {(unsigned)q0 | ((unsigned)q1 << 16), (unsigned)q2 | ((unsigned)q3 << 16)};
      *(uint2*)&Bh[n][bkq * 4] = ph;
      *(uint2*)&Bl[n][bkq * 4] = pl;
    }
    __syncthreads();

    bf16x8 ah[4], al[4];
#pragma unroll
    for (int mi = 0; mi < 4; mi++) {
      const int r = wm * 64 + mi * 16 + l15;
      ah[mi] = *(const bf16x8*)&Ah[r][lg * 8];
      al[mi] = *(const bf16x8*)&Al[r][lg * 8];
    }
#pragma unroll
    for (int ni = 0; ni < 4; ni++) {
      const int n = wn * 64 + ni * 16 + l15;
      const bf16x8 bh = *(const bf16x8*)&Bh[n][lg * 8];
      const bf16x8 bl = *(const bf16x8*)&Bl[n][lg * 8];
#pragma unroll
      for (int mi = 0; mi < 4; mi++) {
        acc[mi][ni] = __builtin_amdgcn_mfma_f32_16x16x32_bf16(ah[mi], bh, acc[mi][ni], 0, 0, 0);
        acc[mi][ni] = __builtin_amdgcn_mfma_f32_16x16x32_bf16(ah[mi], bl, acc[mi][ni], 0, 0, 0);
        acc[mi][ni] = __builtin_amdgcn_mfma_f32_16x16x32_bf16(al[mi], bh, acc[mi][ni], 0, 0, 0);
      }
    }
    __syncthreads();
  }

#pragma unroll
  for (int mi = 0; mi < 4; mi++) {
#pragma unroll
    for (int rr = 0; rr < 4; rr++) {
      const int m = m0 + wm * 64 + mi * 16 + lg * 4 + rr;
      if (m >= ce) continue;
      const int ent  = list[e * T + m];
      const int tok  = ent >> 2;
      const int slot = ent & 3;
      float* drow = downb + ((size_t)tok * TK + slot) * H;
#pragma unroll
      for (int ni = 0; ni < 4; ni++) {
        const int n = n0 + wn * 64 + ni * 16 + l15;
        drow[n] = acc[mi][ni][rr];
      }
    }
  }
}

// ---------------------------------------------------------------------------
// Combine: unchanged from round 1.
// ---------------------------------------------------------------------------
__global__ __launch_bounds__(256) void combine_kernel(
    const float* __restrict__ x, const float* __restrict__ downb,
    const float* __restrict__ wk4, const float* __restrict__ zerow,
    float* __restrict__ out)
{
  const int idx = blockIdx.x * 256 + threadIdx.x;
  const int t   = idx >> 9;
  const int h   = (idx & 511) * 4;

  const float w0 = wk4[t * TK + 0];
  const float w1 = wk4[t * TK + 1];
  const float w2 = wk4[t * TK + 2];
  const float w3 = wk4[t * TK + 3];
  const float zw = zerow[t];

  const float4 xv = *(const float4*)(x + (size_t)t * H + h);
  const float4 d0 = *(const float4*)(downb + ((size_t)t * TK + 0) * H + h);
  const float4 d1 = *(const float4*)(downb + ((size_t)t * TK + 1) * H + h);
  const float4 d2 = *(const float4*)(downb + ((size_t)t * TK + 2) * H + h);
  const float4 d3 = *(const float4*)(downb + ((size_t)t * TK + 3) * H + h);

  float4 o;
  o.x = w0 * d0.x + w1 * d1.x + w2 * d2.x + w3 * d3.x + zw * xv.x;
  o.y = w0 * d0.y + w1 * d1.y + w2 * d2.y + w3 * d3.y + zw * xv.y;
  o.z = w0 * d0.z + w1 * d1.z + w2 * d2.z + w3 * d3.z + zw * xv.z;
  o.w = w0 * d0.w + w1 * d1.w + w2 * d2.w + w3 * d3.w + zw * xv.w;
  *(float4*)(out + (size_t)t * H + h) = o;
}

// ---------------------------------------------------------------------------
extern "C" void kernel_launch(void* const* d_in, const int* in_sizes, int n_in,
                              void* d_out, int out_size, void* d_ws, size_t ws_size,
                              hipStream_t stream) {
  const float* x    = (const float*)d_in[0];
  const float* rw   = (const float*)d_in[1];
  const float* bias = (const float*)d_in[2];
  const float* wg   = (const float*)d_in[3];
  const float* wu   = (const float*)d_in[4];
  const float* wd   = (const float*)d_in[5];
  float* out = (float*)d_out;

  char* ws = (char*)d_ws;
  size_t off = 0;
  auto alloc = [&](size_t bytes) {
    void* p = ws + off;
    off = (off + bytes + 255) & ~(size_t)255;
    return p;
  };
  int*   cnt    = (int*)  alloc(E * sizeof(int));
  int*   list   = (int*)  alloc((size_t)E * T * sizeof(int));
  float* wk4    = (float*)alloc((size_t)T * TK * sizeof(float));
  float* zerow  = (float*)alloc((size_t)T * sizeof(float));
  u16*   mid_hi = (u16*)  alloc((size_t)E * T * I * sizeof(u16));   // 16 MB
  u16*   mid_lo = (u16*)  alloc((size_t)E * T * I * sizeof(u16));   // 16 MB
  float* downb  = (float*)alloc((size_t)T * TK * H * sizeof(float)); // 32 MB
  (void)ws_size;

  hipMemsetAsync(cnt, 0, E * sizeof(int), stream);

  router_kernel<<<T, 256, 0, stream>>>(x, rw, bias, cnt, list, wk4, zerow);

  gateup_kernel<<<dim3(T / 128, I / 128, E), 256, 0, stream>>>(
      x, wg, wu, cnt, list, mid_hi, mid_lo);

  down_kernel<<<dim3(T / 128, H / 128, E), 256, 0, stream>>>(
      mid_hi, mid_lo, wd, cnt, list, downb);

  combine_kernel<<<(T * H / 4) / 256, 256, 0, stream>>>(
      x, downb, wk4, zerow, out);
}

// Round 5
// 315.142 us; speedup vs baseline: 3.1294x; 1.6197x over previous
//
#include <hip/hip_runtime.h>
#include <hip/hip_bf16.h>
#include <math.h>

constexpr int T   = 1024;
constexpr int H   = 2048;
constexpr int I   = 1024;
constexpr int E   = 8;
constexpr int NEZ = 16;   // E + Z
constexpr int TK  = 4;    // TOP_K

typedef short bf16x8 __attribute__((ext_vector_type(8)));
typedef float f32x4  __attribute__((ext_vector_type(4)));
typedef unsigned short u16;
typedef u16 u16x4 __attribute__((ext_vector_type(4)));
typedef u16 u16x8 __attribute__((ext_vector_type(8)));

__device__ __forceinline__ u16 bf16rn(float x) {
  unsigned u = __builtin_bit_cast(unsigned, x);
  u = u + 0x7FFFu + ((u >> 16) & 1u);
  return (u16)(u >> 16);
}
__device__ __forceinline__ float bf16tof(u16 h) {
  return __builtin_bit_cast(float, (unsigned)h << 16);
}

// async global->LDS, 16B per lane; LDS dest = wave-uniform base + lane*16
__device__ __forceinline__ void g2l16(const void* g, void* l) {
  __builtin_amdgcn_global_load_lds(
      (const __attribute__((address_space(1))) unsigned int*)g,
      (__attribute__((address_space(3))) unsigned int*)l, 16, 0, 0);
}

// ---------------------------------------------------------------------------
// prep_x: split x into bf16 hi/lo planes [T][H]
// ---------------------------------------------------------------------------
__global__ __launch_bounds__(256) void prep_x_kernel(
    const float* __restrict__ x, u16* __restrict__ xh, u16* __restrict__ xl)
{
  const int idx = (blockIdx.x * 256 + threadIdx.x) * 4;
  const float4 v = *(const float4*)(x + idx);
  u16x4 h, l;
  const float vv[4] = {v.x, v.y, v.z, v.w};
#pragma unroll
  for (int i = 0; i < 4; i++) {
    const u16 hh = bf16rn(vv[i]);
    h[i] = hh;
    l[i] = bf16rn(vv[i] - bf16tof(hh));
  }
  *(u16x4*)(xh + idx) = h;
  *(u16x4*)(xl + idx) = l;
}

// ---------------------------------------------------------------------------
// Weight prep: convert+transpose one 32k x 64n tile into lane-ordered
// microtiles. Microtile (kt,ntg) = 1KB: lane L holds elems
// (n = ntg*16 + (L&15), k = kt*32 + (L>>4)*8 + j), j=0..7.
// Plane layout [e][kt][ntg][64][8].
// ---------------------------------------------------------------------------
template <int KDIM, int NDIM>
__device__ __forceinline__ void prep_tile(
    const float* __restrict__ src, u16* __restrict__ dh, u16* __restrict__ dl,
    int ei, int kt, int nb)
{
  const int k0 = kt * 32, nn0 = nb * 64;
  __shared__ float Lt[32][65];
  const int tid = threadIdx.x;
#pragma unroll
  for (int r = 0; r < 2; r++) {
    const int f = tid + r * 256;
    const int k = f >> 4, nc = (f & 15) * 4;
    const float4 v = *(const float4*)(src + (size_t)(k0 + k) * NDIM + nn0 + nc);
    Lt[k][nc] = v.x; Lt[k][nc + 1] = v.y; Lt[k][nc + 2] = v.z; Lt[k][nc + 3] = v.w;
  }
  __syncthreads();

  const int w = tid >> 6, lane = tid & 63;
  const int l15 = lane & 15, lg = lane >> 4;
  const int ntg = (nn0 >> 4) + w;
  u16x8 h8, l8;
#pragma unroll
  for (int j = 0; j < 8; j++) {
    const float v = Lt[lg * 8 + j][w * 16 + l15];
    const u16 hh = bf16rn(v);
    h8[j] = hh;
    l8[j] = bf16rn(v - bf16tof(hh));
  }
  const size_t base =
      ((size_t)((size_t)ei * (KDIM >> 5) + kt) * (NDIM >> 4) + ntg) * 512 +
      (size_t)lane * 8;
  *(u16x8*)(dh + base) = h8;
  *(u16x8*)(dl + base) = l8;
}

// gate+up planes: K=H=2048, N=I=1024. grid (1024, 16): 64 kt x 16 nb.
__global__ __launch_bounds__(256) void prep_gu_kernel(
    const float* __restrict__ wg, const float* __restrict__ wu,
    u16* __restrict__ bgh, u16* __restrict__ bgl,
    u16* __restrict__ buh, u16* __restrict__ bul)
{
  const int z = blockIdx.y;
  const float* src; u16 *dh, *dl;
  if (z < 8) { src = wg + (size_t)z * H * I;       dh = bgh; dl = bgl; }
  else       { src = wu + (size_t)(z - 8) * H * I; dh = buh; dl = bul; }
  prep_tile<H, I>(src, dh, dl, z & 7, blockIdx.x >> 4, blockIdx.x & 15);
}

// down planes: K=I=1024, N=H=2048. grid (1024, 8): 32 kt x 32 nb.
__global__ __launch_bounds__(256) void prep_d_kernel(
    const float* __restrict__ wd, u16* __restrict__ bdh, u16* __restrict__ bdl)
{
  const int ei = blockIdx.y;
  prep_tile<I, H>(wd + (size_t)ei * I * H, bdh, bdl, ei,
                  blockIdx.x >> 5, blockIdx.x & 31);
}

// ---------------------------------------------------------------------------
// Router (unchanged, fp32-exact selection).
// ---------------------------------------------------------------------------
__global__ __launch_bounds__(256) void router_kernel(
    const float* __restrict__ x, const float* __restrict__ rw,
    const float* __restrict__ bias, int* __restrict__ cnt,
    int* __restrict__ list, float* __restrict__ wk4,
    float* __restrict__ zerow)
{
  const int t   = blockIdx.x;
  const int tid = threadIdx.x;
  const float* xt = x + (size_t)t * H;

  float acc[NEZ];
#pragma unroll
  for (int e = 0; e < NEZ; e++) acc[e] = 0.f;

  for (int h = tid; h < H; h += 256) {
    const float xv = xt[h];
#pragma unroll
    for (int e = 0; e < NEZ; e++) acc[e] = fmaf(xv, rw[e * H + h], acc[e]);
  }

#pragma unroll
  for (int e = 0; e < NEZ; e++) {
    float v = acc[e];
#pragma unroll
    for (int off = 32; off >= 1; off >>= 1) v += __shfl_down(v, off, 64);
    acc[e] = v;
  }

  __shared__ float red[4][NEZ];
  const int wv = tid >> 6, ln = tid & 63;
  if (ln == 0) {
#pragma unroll
    for (int e = 0; e < NEZ; e++) red[wv][e] = acc[e];
  }
  __syncthreads();

  if (tid == 0) {
    float l[NEZ];
    float mx = -1e30f;
#pragma unroll
    for (int e = 0; e < NEZ; e++) {
      l[e] = red[0][e] + red[1][e] + red[2][e] + red[3][e];
      mx = fmaxf(mx, l[e]);
    }
    float s = 0.f;
#pragma unroll
    for (int e = 0; e < NEZ; e++) { l[e] = expf(l[e] - mx); s += l[e]; }
    const float inv = 1.f / s;
    float sc[NEZ], sel[NEZ];
#pragma unroll
    for (int e = 0; e < NEZ; e++) {
      sc[e]  = l[e] * inv;
      sel[e] = sc[e] + bias[e];
    }
    float zw = 0.f;
#pragma unroll
    for (int k = 0; k < TK; k++) {
      int best = 0; float bv = sel[0];
#pragma unroll
      for (int e = 1; e < NEZ; e++) {
        if (sel[e] > bv) { bv = sel[e]; best = e; }
      }
      sel[best] = -1e30f;
      const float w = sc[best];
      if (best < E) {
        const int pos = atomicAdd(&cnt[best], 1);
        list[best * T + pos] = (t << 2) | k;
        wk4[t * TK + k] = w;
      } else {
        wk4[t * TK + k] = 0.f;
        zw += w;
      }
    }
    zerow[t] = zw;
  }
}

// ---------------------------------------------------------------------------
// Gate+Up grouped GEMM. Tile 64x64, 4 waves (2x2 of 32x32), K-step 32.
// Pure-copy staging via global_load_lds; 2-phase prefetch; 3-term hi/lo MFMA.
// Grid 2048 = 16m x 16n x 8e logical, XCD-chunked (m innermost).
// ---------------------------------------------------------------------------
__global__ __launch_bounds__(256, 2) void gateup_kernel(
    const u16* __restrict__ xh, const u16* __restrict__ xl,
    const u16* __restrict__ bgh, const u16* __restrict__ bgl,
    const u16* __restrict__ buh, const u16* __restrict__ bul,
    const int* __restrict__ cnt, const int* __restrict__ list,
    u16* __restrict__ mid_hi, u16* __restrict__ mid_lo)
{
  const int p = blockIdx.x;
  const int L = (p & 7) * 256 + (p >> 3);   // bijective XCD-chunk remap
  const int e = L >> 8;
  const int rem = L & 255;
  const int n0 = (rem >> 4) * 64;
  const int m0 = (rem & 15) * 64;
  const int ce = cnt[e];
  if (m0 >= ce) return;

  __shared__ __align__(16) char lds[2 * 24 * 1024];

  const int tid = threadIdx.x;
  const int w = tid >> 6, lane = tid & 63;
  const int l15 = lane & 15, lg = lane >> 4;
  const int wm = w >> 1, wn = w & 1;

  // A staging: this thread stages stream s=w&1 of m-tiles (w>>1) and (w>>1)+2
  int r0 = m0 + (w >> 1) * 16 + l15;       if (r0 >= ce) r0 = ce - 1;
  int r1 = m0 + ((w >> 1) + 2) * 16 + l15; if (r1 >= ce) r1 = ce - 1;
  const int tok0 = list[e * T + r0] >> 2;
  const int tok1 = list[e * T + r1] >> 2;
  const u16* xs = (w & 1) ? xl : xh;
  const char* gA0 = (const char*)(xs + (size_t)tok0 * H + lg * 8);
  const char* gA1 = (const char*)(xs + (size_t)tok1 * H + lg * 8);

  // B staging: wave w stages plane w (gh,gl,uh,ul), n-tiles 0..3
  const u16* pl = (w == 0) ? bgh : (w == 1) ? bgl : (w == 2) ? buh : bul;
  const char* gB = (const char*)(pl + (size_t)e * 64 * 64 * 512 +
                                 (size_t)(n0 >> 4) * 512 + (size_t)lane * 8);

  f32x4 accg[2][2] = {};
  f32x4 accu[2][2] = {};

  constexpr int KSTEPS = H / 32;   // 64

  // prologue: stage step 0 into buf 0
  {
    char* bb = lds;
    g2l16(gA0, bb + w * 1024);
    g2l16(gA1, bb + (4 + w) * 1024);
#pragma unroll
    for (int nt = 0; nt < 4; nt++)
      g2l16(gB + nt * 1024, bb + (8 + nt * 4 + w) * 1024);
  }
  __syncthreads();

  for (int t = 0; t < KSTEPS; t++) {
    if (t + 1 < KSTEPS) {
      char* bb = lds + ((t + 1) & 1) * 24576;
      const int ka = (t + 1) * 64;                    // A byte advance
      g2l16(gA0 + ka, bb + w * 1024);
      g2l16(gA1 + ka, bb + (4 + w) * 1024);
      const char* gBs = gB + (size_t)(t + 1) * 65536; // B byte advance per kt
#pragma unroll
      for (int nt = 0; nt < 4; nt++)
        g2l16(gBs + nt * 1024, bb + (8 + nt * 4 + w) * 1024);
    }

    const char* bp = lds + (t & 1) * 24576;
    bf16x8 ah[2], al[2];
#pragma unroll
    for (int mi = 0; mi < 2; mi++) {
      const int mt = wm * 2 + mi;
      ah[mi] = *(const bf16x8*)(bp + (mt * 2 + 0) * 1024 + lane * 16);
      al[mi] = *(const bf16x8*)(bp + (mt * 2 + 1) * 1024 + lane * 16);
    }
#pragma unroll
    for (int ni = 0; ni < 2; ni++) {
      const int nt = wn * 2 + ni;
      const bf16x8 vgh = *(const bf16x8*)(bp + 8192 + (nt * 4 + 0) * 1024 + lane * 16);
      const bf16x8 vgl = *(const bf16x8*)(bp + 8192 + (nt * 4 + 1) * 1024 + lane * 16);
      const bf16x8 vuh = *(const bf16x8*)(bp + 8192 + (nt * 4 + 2) * 1024 + lane * 16);
      const bf16x8 vul = *(const bf16x8*)(bp + 8192 + (nt * 4 + 3) * 1024 + lane * 16);
#pragma unroll
      for (int mi = 0; mi < 2; mi++) {
        accg[mi][ni] = __builtin_amdgcn_mfma_f32_16x16x32_bf16(ah[mi], vgh, accg[mi][ni], 0, 0, 0);
        accg[mi][ni] = __builtin_amdgcn_mfma_f32_16x16x32_bf16(ah[mi], vgl, accg[mi][ni], 0, 0, 0);
        accg[mi][ni] = __builtin_amdgcn_mfma_f32_16x16x32_bf16(al[mi], vgh, accg[mi][ni], 0, 0, 0);
        accu[mi][ni] = __builtin_amdgcn_mfma_f32_16x16x32_bf16(ah[mi], vuh, accu[mi][ni], 0, 0, 0);
        accu[mi][ni] = __builtin_amdgcn_mfma_f32_16x16x32_bf16(ah[mi], vul, accu[mi][ni], 0, 0, 0);
        accu[mi][ni] = __builtin_amdgcn_mfma_f32_16x16x32_bf16(al[mi], vuh, accu[mi][ni], 0, 0, 0);
      }
    }
    __syncthreads();
  }

  // epilogue: silu(g)*u -> bf16 hi/lo mid
#pragma unroll
  for (int mi = 0; mi < 2; mi++) {
#pragma unroll
    for (int rr = 0; rr < 4; rr++) {
      const int m = m0 + (wm * 2 + mi) * 16 + lg * 4 + rr;
      if (m >= ce) continue;
      const size_t ro = ((size_t)e * T + m) * I;
#pragma unroll
      for (int ni = 0; ni < 2; ni++) {
        const int n = n0 + (wn * 2 + ni) * 16 + l15;
        const float g = accg[mi][ni][rr];
        const float u = accu[mi][ni][rr];
        const float mv = (g / (1.f + expf(-g))) * u;
        const u16 hh = bf16rn(mv);
        mid_hi[ro + n] = hh;
        mid_lo[ro + n] = bf16rn(mv - bf16tof(hh));
      }
    }
  }
}

// ---------------------------------------------------------------------------
// Down grouped GEMM: mid @ wd. Tile 64x64, K=I, 32 steps. Scatter epilogue.
// Grid 4096 = 16m x 32n x 8e logical, XCD-chunked.
// ---------------------------------------------------------------------------
__global__ __launch_bounds__(256, 2) void down_kernel(
    const u16* __restrict__ midh, const u16* __restrict__ midl,
    const u16* __restrict__ bdh, const u16* __restrict__ bdl,
    const int* __restrict__ cnt, const int* __restrict__ list,
    float* __restrict__ downb)
{
  const int p = blockIdx.x;
  const int L = (p & 7) * 512 + (p >> 3);
  const int e = L >> 9;
  const int rem = L & 511;
  const int n0 = (rem >> 4) * 64;
  const int m0 = (rem & 15) * 64;
  const int ce = cnt[e];
  if (m0 >= ce) return;

  __shared__ __align__(16) char lds[2 * 16 * 1024];

  const int tid = threadIdx.x;
  const int w = tid >> 6, lane = tid & 63;
  const int l15 = lane & 15, lg = lane >> 4;
  const int wm = w >> 1, wn = w & 1;

  int r0 = m0 + (w >> 1) * 16 + l15;       if (r0 >= ce) r0 = ce - 1;
  int r1 = m0 + ((w >> 1) + 2) * 16 + l15; if (r1 >= ce) r1 = ce - 1;
  const u16* ms = (w & 1) ? midl : midh;
  const char* gA0 = (const char*)(ms + ((size_t)e * T + r0) * I + lg * 8);
  const char* gA1 = (const char*)(ms + ((size_t)e * T + r1) * I + lg * 8);

  // B: wave stages stream s=w&1, n-tiles (w>>1) and (w>>1)+2
  const u16* pl = (w & 1) ? bdl : bdh;
  const char* gB0 = (const char*)(pl + (size_t)e * 32 * 128 * 512 +
                                  (size_t)((n0 >> 4) + (w >> 1)) * 512 + (size_t)lane * 8);
  const char* gB1 = gB0 + 2 * 1024;

  f32x4 acc[2][2] = {};

  constexpr int KSTEPS = I / 32;   // 32

  {
    char* bb = lds;
    g2l16(gA0, bb + w * 1024);
    g2l16(gA1, bb + (4 + w) * 1024);
    g2l16(gB0, bb + (8 + w) * 1024);
    g2l16(gB1, bb + (8 + 4 + w) * 1024);
  }
  __syncthreads();

  for (int t = 0; t < KSTEPS; t++) {
    if (t + 1 < KSTEPS) {
      char* bb = lds + ((t + 1) & 1) * 16384;
      const int ka = (t + 1) * 64;
      const size_t kb = (size_t)(t + 1) * 131072;   // 128*512 elems * 2B
      g2l16(gA0 + ka, bb + w * 1024);
      g2l16(gA1 + ka, bb + (4 + w) * 1024);
      g2l16(gB0 + kb, bb + (8 + w) * 1024);
      g2l16(gB1 + kb, bb + (8 + 4 + w) * 1024);
    }

    const char* bp = lds + (t & 1) * 16384;
    bf16x8 ah[2], al[2];
#pragma unroll
    for (int mi = 0; mi < 2; mi++) {
      const int mt = wm * 2 + mi;
      ah[mi] = *(const bf16x8*)(bp + (mt * 2 + 0) * 1024 + lane * 16);
      al[mi] = *(const bf16x8*)(bp + (mt * 2 + 1) * 1024 + lane * 16);
    }
#pragma unroll
    for (int ni = 0; ni < 2; ni++) {
      const int nt = wn * 2 + ni;
      const bf16x8 vbh = *(const bf16x8*)(bp + 8192 + (nt * 2 + 0) * 1024 + lane * 16);
      const bf16x8 vbl = *(const bf16x8*)(bp + 8192 + (nt * 2 + 1) * 1024 + lane * 16);
#pragma unroll
      for (int mi = 0; mi < 2; mi++) {
        acc[mi][ni] = __builtin_amdgcn_mfma_f32_16x16x32_bf16(ah[mi], vbh, acc[mi][ni], 0, 0, 0);
        acc[mi][ni] = __builtin_amdgcn_mfma_f32_16x16x32_bf16(ah[mi], vbl, acc[mi][ni], 0, 0, 0);
        acc[mi][ni] = __builtin_amdgcn_mfma_f32_16x16x32_bf16(al[mi], vbh, acc[mi][ni], 0, 0, 0);
      }
    }
    __syncthreads();
  }

#pragma unroll
  for (int mi = 0; mi < 2; mi++) {
#pragma unroll
    for (int rr = 0; rr < 4; rr++) {
      const int m = m0 + (wm * 2 + mi) * 16 + lg * 4 + rr;
      if (m >= ce) continue;
      const int ent  = list[e * T + m];
      const int tok  = ent >> 2;
      const int slot = ent & 3;
      float* drow = downb + ((size_t)tok * TK + slot) * H;
#pragma unroll
      for (int ni = 0; ni < 2; ni++) {
        const int n = n0 + (wn * 2 + ni) * 16 + l15;
        drow[n] = acc[mi][ni][rr];
      }
    }
  }
}

// ---------------------------------------------------------------------------
// Combine (unchanged).
// ---------------------------------------------------------------------------
__global__ __launch_bounds__(256) void combine_kernel(
    const float* __restrict__ x, const float* __restrict__ downb,
    const float* __restrict__ wk4, const float* __restrict__ zerow,
    float* __restrict__ out)
{
  const int idx = blockIdx.x * 256 + threadIdx.x;
  const int t   = idx >> 9;
  const int h   = (idx & 511) * 4;

  const float w0 = wk4[t * TK + 0];
  const float w1 = wk4[t * TK + 1];
  const float w2 = wk4[t * TK + 2];
  const float w3 = wk4[t * TK + 3];
  const float zw = zerow[t];

  const float4 xv = *(const float4*)(x + (size_t)t * H + h);
  const float4 d0 = *(const float4*)(downb + ((size_t)t * TK + 0) * H + h);
  const float4 d1 = *(const float4*)(downb + ((size_t)t * TK + 1) * H + h);
  const float4 d2 = *(const float4*)(downb + ((size_t)t * TK + 2) * H + h);
  const float4 d3 = *(const float4*)(downb + ((size_t)t * TK + 3) * H + h);

  float4 o;
  o.x = w0 * d0.x + w1 * d1.x + w2 * d2.x + w3 * d3.x + zw * xv.x;
  o.y = w0 * d0.y + w1 * d1.y + w2 * d2.y + w3 * d3.y + zw * xv.y;
  o.z = w0 * d0.z + w1 * d1.z + w2 * d2.z + w3 * d3.z + zw * xv.z;
  o.w = w0 * d0.w + w1 * d1.w + w2 * d2.w + w3 * d3.w + zw * xv.w;
  *(float4*)(out + (size_t)t * H + h) = o;
}

// ---------------------------------------------------------------------------
// Workspace plan (total ~168 MiB; aliasing is stream-order safe):
//   P region = 4 planes x 32 MiB:
//     [P+0]      bgh  -> later bdh      (prep_d runs after gateup)
//     [P+32Mi]   bgl  -> later bdl
//     [P+64Mi]   buh  -> later downb    (32 MiB exactly)
//     [P+96Mi]   bul  -> free during down
// ---------------------------------------------------------------------------
extern "C" void kernel_launch(void* const* d_in, const int* in_sizes, int n_in,
                              void* d_out, int out_size, void* d_ws, size_t ws_size,
                              hipStream_t stream) {
  const float* x    = (const float*)d_in[0];
  const float* rw   = (const float*)d_in[1];
  const float* bias = (const float*)d_in[2];
  const float* wg   = (const float*)d_in[3];
  const float* wu   = (const float*)d_in[4];
  const float* wd   = (const float*)d_in[5];
  float* out = (float*)d_out;

  char* ws = (char*)d_ws;
  size_t off = 0;
  auto alloc = [&](size_t bytes) {
    void* p = ws + off;
    off = (off + bytes + 1023) & ~(size_t)1023;
    return p;
  };
  int*   cnt   = (int*)  alloc(E * sizeof(int));
  int*   list  = (int*)  alloc((size_t)E * T * sizeof(int));
  float* wk4   = (float*)alloc((size_t)T * TK * sizeof(float));
  float* zerow = (float*)alloc((size_t)T * sizeof(float));
  u16*   xh    = (u16*)  alloc((size_t)T * H * sizeof(u16));
  u16*   xl    = (u16*)  alloc((size_t)T * H * sizeof(u16));
  constexpr size_t PLANE = (size_t)E * H * I * sizeof(u16);  // 32 MiB
  char*  P     = (char*) alloc(4 * PLANE);
  u16*   bgh   = (u16*)(P);
  u16*   bgl   = (u16*)(P + PLANE);
  u16*   buh   = (u16*)(P + 2 * PLANE);
  u16*   bul   = (u16*)(P + 3 * PLANE);
  u16*   bdh   = bgh;                    // alias: written after gateup
  u16*   bdl   = bgl;
  float* downb = (float*)(P + 2 * PLANE);  // alias buh: written during down
  u16*   midh  = (u16*)  alloc((size_t)E * T * I * sizeof(u16));
  u16*   midl  = (u16*)  alloc((size_t)E * T * I * sizeof(u16));
  (void)ws_size;

  hipMemsetAsync(cnt, 0, E * sizeof(int), stream);

  prep_x_kernel<<<(T * H / 4) / 256, 256, 0, stream>>>(x, xh, xl);
  prep_gu_kernel<<<dim3(1024, 16), 256, 0, stream>>>(
      wg, wu, bgh, bgl, buh, bul);
  router_kernel<<<T, 256, 0, stream>>>(x, rw, bias, cnt, list, wk4, zerow);

  gateup_kernel<<<2048, 256, 0, stream>>>(
      xh, xl, bgh, bgl, buh, bul, cnt, list, midh, midl);

  prep_d_kernel<<<dim3(1024, 8), 256, 0, stream>>>(wd, bdh, bdl);

  down_kernel<<<4096, 256, 0, stream>>>(
      midh, midl, bdh, bdl, cnt, list, downb);
  combine_kernel<<<(T * H / 4) / 256, 256, 0, stream>>>(
      x, downb, wk4, zerow, out);
}

// Round 6
// 258.839 us; speedup vs baseline: 3.8101x; 1.2175x over previous
//
#include <hip/hip_runtime.h>
#include <hip/hip_bf16.h>
#include <math.h>

constexpr int T   = 1024;
constexpr int H   = 2048;
constexpr int I   = 1024;
constexpr int E   = 8;
constexpr int NEZ = 16;   // E + Z
constexpr int TK  = 4;    // TOP_K

typedef short bf16x8 __attribute__((ext_vector_type(8)));
typedef float f32x4  __attribute__((ext_vector_type(4)));
typedef unsigned short u16;
typedef u16 u16x4 __attribute__((ext_vector_type(4)));
typedef u16 u16x8 __attribute__((ext_vector_type(8)));

#define VMCNT(n) asm volatile("s_waitcnt vmcnt(" #n ")" ::: "memory")

__device__ __forceinline__ u16 bf16rn(float x) {
  unsigned u = __builtin_bit_cast(unsigned, x);
  u = u + 0x7FFFu + ((u >> 16) & 1u);
  return (u16)(u >> 16);
}
__device__ __forceinline__ float bf16tof(u16 h) {
  return __builtin_bit_cast(float, (unsigned)h << 16);
}

// async global->LDS, 16B per lane; LDS dest = wave-uniform base + lane*16
__device__ __forceinline__ void g2l16(const void* g, void* l) {
  __builtin_amdgcn_global_load_lds(
      (const __attribute__((address_space(1))) unsigned int*)g,
      (__attribute__((address_space(3))) unsigned int*)l, 16, 0, 0);
}

// ---------------------------------------------------------------------------
// prep_x: split x into bf16 hi/lo planes [T][H]
// ---------------------------------------------------------------------------
__global__ __launch_bounds__(256) void prep_x_kernel(
    const float* __restrict__ x, u16* __restrict__ xh, u16* __restrict__ xl)
{
  const int idx = (blockIdx.x * 256 + threadIdx.x) * 4;
  const float4 v = *(const float4*)(x + idx);
  u16x4 h, l;
  const float vv[4] = {v.x, v.y, v.z, v.w};
#pragma unroll
  for (int i = 0; i < 4; i++) {
    const u16 hh = bf16rn(vv[i]);
    h[i] = hh;
    l[i] = bf16rn(vv[i] - bf16tof(hh));
  }
  *(u16x4*)(xh + idx) = h;
  *(u16x4*)(xl + idx) = l;
}

// ---------------------------------------------------------------------------
// Weight prep: convert+transpose one 32k x 64n tile into lane-ordered
// microtiles. Microtile (kt,ntg) = 1KB: lane L holds elems
// (n = ntg*16 + (L&15), k = kt*32 + (L>>4)*8 + j), j=0..7.
// Plane layout [e][kt][ntg][64][8].
// ---------------------------------------------------------------------------
template <int KDIM, int NDIM>
__device__ __forceinline__ void prep_tile(
    const float* __restrict__ src, u16* __restrict__ dh, u16* __restrict__ dl,
    int ei, int kt, int nb)
{
  const int k0 = kt * 32, nn0 = nb * 64;
  __shared__ float Lt[32][65];
  const int tid = threadIdx.x;
#pragma unroll
  for (int r = 0; r < 2; r++) {
    const int f = tid + r * 256;
    const int k = f >> 4, nc = (f & 15) * 4;
    const float4 v = *(const float4*)(src + (size_t)(k0 + k) * NDIM + nn0 + nc);
    Lt[k][nc] = v.x; Lt[k][nc + 1] = v.y; Lt[k][nc + 2] = v.z; Lt[k][nc + 3] = v.w;
  }
  __syncthreads();

  const int w = tid >> 6, lane = tid & 63;
  const int l15 = lane & 15, lg = lane >> 4;
  const int ntg = (nn0 >> 4) + w;
  u16x8 h8, l8;
#pragma unroll
  for (int j = 0; j < 8; j++) {
    const float v = Lt[lg * 8 + j][w * 16 + l15];
    const u16 hh = bf16rn(v);
    h8[j] = hh;
    l8[j] = bf16rn(v - bf16tof(hh));
  }
  const size_t base =
      ((size_t)((size_t)ei * (KDIM >> 5) + kt) * (NDIM >> 4) + ntg) * 512 +
      (size_t)lane * 8;
  *(u16x8*)(dh + base) = h8;
  *(u16x8*)(dl + base) = l8;
}

// gate+up planes: K=H=2048, N=I=1024. grid (1024, 16): 64 kt x 16 nb.
__global__ __launch_bounds__(256) void prep_gu_kernel(
    const float* __restrict__ wg, const float* __restrict__ wu,
    u16* __restrict__ bgh, u16* __restrict__ bgl,
    u16* __restrict__ buh, u16* __restrict__ bul)
{
  const int z = blockIdx.y;
  const float* src; u16 *dh, *dl;
  if (z < 8) { src = wg + (size_t)z * H * I;       dh = bgh; dl = bgl; }
  else       { src = wu + (size_t)(z - 8) * H * I; dh = buh; dl = bul; }
  prep_tile<H, I>(src, dh, dl, z & 7, blockIdx.x >> 4, blockIdx.x & 15);
}

// down planes: K=I=1024, N=H=2048. grid (1024, 8): 32 kt x 32 nb.
__global__ __launch_bounds__(256) void prep_d_kernel(
    const float* __restrict__ wd, u16* __restrict__ bdh, u16* __restrict__ bdl)
{
  const int ei = blockIdx.y;
  prep_tile<I, H>(wd + (size_t)ei * I * H, bdh, bdl, ei,
                  blockIdx.x >> 5, blockIdx.x & 31);
}

// ---------------------------------------------------------------------------
// Router (unchanged, fp32-exact selection).
// ---------------------------------------------------------------------------
__global__ __launch_bounds__(256) void router_kernel(
    const float* __restrict__ x, const float* __restrict__ rw,
    const float* __restrict__ bias, int* __restrict__ cnt,
    int* __restrict__ list, float* __restrict__ wk4,
    float* __restrict__ zerow)
{
  const int t   = blockIdx.x;
  const int tid = threadIdx.x;
  const float* xt = x + (size_t)t * H;

  float acc[NEZ];
#pragma unroll
  for (int e = 0; e < NEZ; e++) acc[e] = 0.f;

  for (int h = tid; h < H; h += 256) {
    const float xv = xt[h];
#pragma unroll
    for (int e = 0; e < NEZ; e++) acc[e] = fmaf(xv, rw[e * H + h], acc[e]);
  }

#pragma unroll
  for (int e = 0; e < NEZ; e++) {
    float v = acc[e];
#pragma unroll
    for (int off = 32; off >= 1; off >>= 1) v += __shfl_down(v, off, 64);
    acc[e] = v;
  }

  __shared__ float red[4][NEZ];
  const int wv = tid >> 6, ln = tid & 63;
  if (ln == 0) {
#pragma unroll
    for (int e = 0; e < NEZ; e++) red[wv][e] = acc[e];
  }
  __syncthreads();

  if (tid == 0) {
    float l[NEZ];
    float mx = -1e30f;
#pragma unroll
    for (int e = 0; e < NEZ; e++) {
      l[e] = red[0][e] + red[1][e] + red[2][e] + red[3][e];
      mx = fmaxf(mx, l[e]);
    }
    float s = 0.f;
#pragma unroll
    for (int e = 0; e < NEZ; e++) { l[e] = expf(l[e] - mx); s += l[e]; }
    const float inv = 1.f / s;
    float sc[NEZ], sel[NEZ];
#pragma unroll
    for (int e = 0; e < NEZ; e++) {
      sc[e]  = l[e] * inv;
      sel[e] = sc[e] + bias[e];
    }
    float zw = 0.f;
#pragma unroll
    for (int k = 0; k < TK; k++) {
      int best = 0; float bv = sel[0];
#pragma unroll
      for (int e = 1; e < NEZ; e++) {
        if (sel[e] > bv) { bv = sel[e]; best = e; }
      }
      sel[best] = -1e30f;
      const float w = sc[best];
      if (best < E) {
        const int pos = atomicAdd(&cnt[best], 1);
        list[best * T + pos] = (t << 2) | k;
        wk4[t * TK + k] = w;
      } else {
        wk4[t * TK + k] = 0.f;
        zw += w;
      }
    }
    zerow[t] = zw;
  }
}

// ---------------------------------------------------------------------------
// Gate+Up grouped GEMM. Tile 64x64, 4 waves (2x2 of 32x32), K-step 32.
// T3+T4 pipeline: 3 LDS buffers, prefetch depth 2, counted vmcnt(6),
// raw s_barrier (one per K-step). Per iter: vmcnt(6); barrier; stage(t+2);
// ds_read buf[t%3]; MFMA. Stage after the barrier targets buf[(t-1)%3],
// whose readers drained (lgkm before their MFMA) before passing the barrier.
// Grid 2048 = (m slow, n fast) x 8e XCD-chunked: live blocks (m<4) first.
// ---------------------------------------------------------------------------
__global__ __launch_bounds__(256, 2) void gateup_kernel(
    const u16* __restrict__ xh, const u16* __restrict__ xl,
    const u16* __restrict__ bgh, const u16* __restrict__ bgl,
    const u16* __restrict__ buh, const u16* __restrict__ bul,
    const int* __restrict__ cnt, const int* __restrict__ list,
    u16* __restrict__ mid_hi, u16* __restrict__ mid_lo)
{
  const int p = blockIdx.x;
  const int L = (p & 7) * 256 + (p >> 3);   // bijective XCD-chunk remap
  const int e = L >> 8;
  const int rem = L & 255;
  const int m0 = (rem >> 4) * 64;   // m slow: live blocks dispatch first
  const int n0 = (rem & 15) * 64;
  const int ce = cnt[e];
  if (m0 >= ce) return;

  __shared__ __align__(16) char lds[3 * 24 * 1024];

  const int tid = threadIdx.x;
  const int w = tid >> 6, lane = tid & 63;
  const int l15 = lane & 15, lg = lane >> 4;
  const int wm = w >> 1, wn = w & 1;

  // A staging: this thread stages stream s=w&1 of m-tiles (w>>1) and (w>>1)+2
  int r0 = m0 + (w >> 1) * 16 + l15;       if (r0 >= ce) r0 = ce - 1;
  int r1 = m0 + ((w >> 1) + 2) * 16 + l15; if (r1 >= ce) r1 = ce - 1;
  const int tok0 = list[e * T + r0] >> 2;
  const int tok1 = list[e * T + r1] >> 2;
  const u16* xs = (w & 1) ? xl : xh;
  const char* gA0 = (const char*)(xs + (size_t)tok0 * H + lg * 8);
  const char* gA1 = (const char*)(xs + (size_t)tok1 * H + lg * 8);

  // B staging: wave w stages plane w (gh,gl,uh,ul), n-tiles 0..3
  const u16* pl = (w == 0) ? bgh : (w == 1) ? bgl : (w == 2) ? buh : bul;
  const char* gB = (const char*)(pl + (size_t)e * 64 * 64 * 512 +
                                 (size_t)(n0 >> 4) * 512 + (size_t)lane * 8);

  f32x4 accg[2][2] = {};
  f32x4 accu[2][2] = {};

  constexpr int KSTEPS = H / 32;   // 64

  auto stage = [&](int ts) {
    char* bb = lds + (ts % 3) * 24576;
    const int ka = ts * 64;                          // A byte advance
    g2l16(gA0 + ka, bb + w * 1024);
    g2l16(gA1 + ka, bb + (4 + w) * 1024);
    const char* gBs = gB + (size_t)ts * 65536;       // B byte advance per kt
#pragma unroll
    for (int nt = 0; nt < 4; nt++)
      g2l16(gBs + nt * 1024, bb + (8 + nt * 4 + w) * 1024);
  };

  // prologue: prefetch steps 0 and 1 (6 loads each per wave)
  stage(0);
  stage(1);

  for (int t = 0; t < KSTEPS; t++) {
    // wait for stage(t): leave stage(t+1)'s 6 loads in flight
    if (t < KSTEPS - 1) { VMCNT(6); } else { VMCNT(0); }
    __builtin_amdgcn_s_barrier();
    if (t + 2 < KSTEPS) stage(t + 2);

    const char* bp = lds + (t % 3) * 24576;
    bf16x8 ah[2], al[2];
#pragma unroll
    for (int mi = 0; mi < 2; mi++) {
      const int mt = wm * 2 + mi;
      ah[mi] = *(const bf16x8*)(bp + (mt * 2 + 0) * 1024 + lane * 16);
      al[mi] = *(const bf16x8*)(bp + (mt * 2 + 1) * 1024 + lane * 16);
    }
#pragma unroll
    for (int ni = 0; ni < 2; ni++) {
      const int nt = wn * 2 + ni;
      const bf16x8 vgh = *(const bf16x8*)(bp + 8192 + (nt * 4 + 0) * 1024 + lane * 16);
      const bf16x8 vgl = *(const bf16x8*)(bp + 8192 + (nt * 4 + 1) * 1024 + lane * 16);
      const bf16x8 vuh = *(const bf16x8*)(bp + 8192 + (nt * 4 + 2) * 1024 + lane * 16);
      const bf16x8 vul = *(const bf16x8*)(bp + 8192 + (nt * 4 + 3) * 1024 + lane * 16);
#pragma unroll
      for (int mi = 0; mi < 2; mi++) {
        accg[mi][ni] = __builtin_amdgcn_mfma_f32_16x16x32_bf16(ah[mi], vgh, accg[mi][ni], 0, 0, 0);
        accg[mi][ni] = __builtin_amdgcn_mfma_f32_16x16x32_bf16(ah[mi], vgl, accg[mi][ni], 0, 0, 0);
        accg[mi][ni] = __builtin_amdgcn_mfma_f32_16x16x32_bf16(al[mi], vgh, accg[mi][ni], 0, 0, 0);
        accu[mi][ni] = __builtin_amdgcn_mfma_f32_16x16x32_bf16(ah[mi], vuh, accu[mi][ni], 0, 0, 0);
        accu[mi][ni] = __builtin_amdgcn_mfma_f32_16x16x32_bf16(ah[mi], vul, accu[mi][ni], 0, 0, 0);
        accu[mi][ni] = __builtin_amdgcn_mfma_f32_16x16x32_bf16(al[mi], vuh, accu[mi][ni], 0, 0, 0);
      }
    }
  }

  // epilogue: silu(g)*u -> bf16 hi/lo mid
#pragma unroll
  for (int mi = 0; mi < 2; mi++) {
#pragma unroll
    for (int rr = 0; rr < 4; rr++) {
      const int m = m0 + (wm * 2 + mi) * 16 + lg * 4 + rr;
      if (m >= ce) continue;
      const size_t ro = ((size_t)e * T + m) * I;
#pragma unroll
      for (int ni = 0; ni < 2; ni++) {
        const int n = n0 + (wn * 2 + ni) * 16 + l15;
        const float g = accg[mi][ni][rr];
        const float u = accu[mi][ni][rr];
        const float mv = (g / (1.f + expf(-g))) * u;
        const u16 hh = bf16rn(mv);
        mid_hi[ro + n] = hh;
        mid_lo[ro + n] = bf16rn(mv - bf16tof(hh));
      }
    }
  }
}

// ---------------------------------------------------------------------------
// Down grouped GEMM: mid @ wd. Tile 64x64, K=I, 32 steps. Same T3+T4
// pipeline (4 loads/stage -> vmcnt(4)). 3 blocks/CU. Scatter epilogue.
// Grid 4096 = (m slow, n fast) x 8e, XCD-chunked.
// ---------------------------------------------------------------------------
__global__ __launch_bounds__(256, 3) void down_kernel(
    const u16* __restrict__ midh, const u16* __restrict__ midl,
    const u16* __restrict__ bdh, const u16* __restrict__ bdl,
    const int* __restrict__ cnt, const int* __restrict__ list,
    float* __restrict__ downb)
{
  const int p = blockIdx.x;
  const int L = (p & 7) * 512 + (p >> 3);
  const int e = L >> 9;
  const int rem = L & 511;
  const int m0 = (rem >> 5) * 64;   // m slow: live blocks dispatch first
  const int n0 = (rem & 31) * 64;
  const int ce = cnt[e];
  if (m0 >= ce) return;

  __shared__ __align__(16) char lds[3 * 16 * 1024];

  const int tid = threadIdx.x;
  const int w = tid >> 6, lane = tid & 63;
  const int l15 = lane & 15, lg = lane >> 4;
  const int wm = w >> 1, wn = w & 1;

  int r0 = m0 + (w >> 1) * 16 + l15;       if (r0 >= ce) r0 = ce - 1;
  int r1 = m0 + ((w >> 1) + 2) * 16 + l15; if (r1 >= ce) r1 = ce - 1;
  const u16* ms = (w & 1) ? midl : midh;
  const char* gA0 = (const char*)(ms + ((size_t)e * T + r0) * I + lg * 8);
  const char* gA1 = (const char*)(ms + ((size_t)e * T + r1) * I + lg * 8);

  // B: wave stages stream s=w&1, n-tiles (w>>1) and (w>>1)+2
  const u16* pl = (w & 1) ? bdl : bdh;
  const char* gB0 = (const char*)(pl + (size_t)e * 32 * 128 * 512 +
                                  (size_t)((n0 >> 4) + (w >> 1)) * 512 + (size_t)lane * 8);
  const char* gB1 = gB0 + 2 * 1024;

  f32x4 acc[2][2] = {};

  constexpr int KSTEPS = I / 32;   // 32

  auto stage = [&](int ts) {
    char* bb = lds + (ts % 3) * 16384;
    const int ka = ts * 64;
    const size_t kb = (size_t)ts * 131072;   // 128*512 elems * 2B
    g2l16(gA0 + ka, bb + w * 1024);
    g2l16(gA1 + ka, bb + (4 + w) * 1024);
    g2l16(gB0 + kb, bb + (8 + w) * 1024);
    g2l16(gB1 + kb, bb + (8 + 4 + w) * 1024);
  };

  stage(0);
  stage(1);

  for (int t = 0; t < KSTEPS; t++) {
    if (t < KSTEPS - 1) { VMCNT(4); } else { VMCNT(0); }
    __builtin_amdgcn_s_barrier();
    if (t + 2 < KSTEPS) stage(t + 2);

    const char* bp = lds + (t % 3) * 16384;
    bf16x8 ah[2], al[2];
#pragma unroll
    for (int mi = 0; mi < 2; mi++) {
      const int mt = wm * 2 + mi;
      ah[mi] = *(const bf16x8*)(bp + (mt * 2 + 0) * 1024 + lane * 16);
      al[mi] = *(const bf16x8*)(bp + (mt * 2 + 1) * 1024 + lane * 16);
    }
#pragma unroll
    for (int ni = 0; ni < 2; ni++) {
      const int nt = wn * 2 + ni;
      const bf16x8 vbh = *(const bf16x8*)(bp + 8192 + (nt * 2 + 0) * 1024 + lane * 16);
      const bf16x8 vbl = *(const bf16x8*)(bp + 8192 + (nt * 2 + 1) * 1024 + lane * 16);
#pragma unroll
      for (int mi = 0; mi < 2; mi++) {
        acc[mi][ni] = __builtin_amdgcn_mfma_f32_16x16x32_bf16(ah[mi], vbh, acc[mi][ni], 0, 0, 0);
        acc[mi][ni] = __builtin_amdgcn_mfma_f32_16x16x32_bf16(ah[mi], vbl, acc[mi][ni], 0, 0, 0);
        acc[mi][ni] = __builtin_amdgcn_mfma_f32_16x16x32_bf16(al[mi], vbh, acc[mi][ni], 0, 0, 0);
      }
    }
  }

#pragma unroll
  for (int mi = 0; mi < 2; mi++) {
#pragma unroll
    for (int rr = 0; rr < 4; rr++) {
      const int m = m0 + (wm * 2 + mi) * 16 + lg * 4 + rr;
      if (m >= ce) continue;
      const int ent  = list[e * T + m];
      const int tok  = ent >> 2;
      const int slot = ent & 3;
      float* drow = downb + ((size_t)tok * TK + slot) * H;
#pragma unroll
      for (int ni = 0; ni < 2; ni++) {
        const int n = n0 + (wn * 2 + ni) * 16 + l15;
        drow[n] = acc[mi][ni][rr];
      }
    }
  }
}

// ---------------------------------------------------------------------------
// Combine (unchanged).
// ---------------------------------------------------------------------------
__global__ __launch_bounds__(256) void combine_kernel(
    const float* __restrict__ x, const float* __restrict__ downb,
    const float* __restrict__ wk4, const float* __restrict__ zerow,
    float* __restrict__ out)
{
  const int idx = blockIdx.x * 256 + threadIdx.x;
  const int t   = idx >> 9;
  const int h   = (idx & 511) * 4;

  const float w0 = wk4[t * TK + 0];
  const float w1 = wk4[t * TK + 1];
  const float w2 = wk4[t * TK + 2];
  const float w3 = wk4[t * TK + 3];
  const float zw = zerow[t];

  const float4 xv = *(const float4*)(x + (size_t)t * H + h);
  const float4 d0 = *(const float4*)(downb + ((size_t)t * TK + 0) * H + h);
  const float4 d1 = *(const float4*)(downb + ((size_t)t * TK + 1) * H + h);
  const float4 d2 = *(const float4*)(downb + ((size_t)t * TK + 2) * H + h);
  const float4 d3 = *(const float4*)(downb + ((size_t)t * TK + 3) * H + h);

  float4 o;
  o.x = w0 * d0.x + w1 * d1.x + w2 * d2.x + w3 * d3.x + zw * xv.x;
  o.y = w0 * d0.y + w1 * d1.y + w2 * d2.y + w3 * d3.y + zw * xv.y;
  o.z = w0 * d0.z + w1 * d1.z + w2 * d2.z + w3 * d3.z + zw * xv.z;
  o.w = w0 * d0.w + w1 * d1.w + w2 * d2.w + w3 * d3.w + zw * xv.w;
  *(float4*)(out + (size_t)t * H + h) = o;
}

// ---------------------------------------------------------------------------
// Workspace plan (total ~168 MiB; aliasing is stream-order safe):
//   P region = 4 planes x 32 MiB:
//     [P+0]      bgh  -> later bdh      (prep_d runs after gateup)
//     [P+32Mi]   bgl  -> later bdl
//     [P+64Mi]   buh  -> later downb    (32 MiB exactly)
//     [P+96Mi]   bul  -> free during down
// ---------------------------------------------------------------------------
extern "C" void kernel_launch(void* const* d_in, const int* in_sizes, int n_in,
                              void* d_out, int out_size, void* d_ws, size_t ws_size,
                              hipStream_t stream) {
  const float* x    = (const float*)d_in[0];
  const float* rw   = (const float*)d_in[1];
  const float* bias = (const float*)d_in[2];
  const float* wg   = (const float*)d_in[3];
  const float* wu   = (const float*)d_in[4];
  const float* wd   = (const float*)d_in[5];
  float* out = (float*)d_out;

  char* ws = (char*)d_ws;
  size_t off = 0;
  auto alloc = [&](size_t bytes) {
    void* p = ws + off;
    off = (off + bytes + 1023) & ~(size_t)1023;
    return p;
  };
  int*   cnt   = (int*)  alloc(E * sizeof(int));
  int*   list  = (int*)  alloc((size_t)E * T * sizeof(int));
  float* wk4   = (float*)alloc((size_t)T * TK * sizeof(float));
  float* zerow = (float*)alloc((size_t)T * sizeof(float));
  u16*   xh    = (u16*)  alloc((size_t)T * H * sizeof(u16));
  u16*   xl    = (u16*)  alloc((size_t)T * H * sizeof(u16));
  constexpr size_t PLANE = (size_t)E * H * I * sizeof(u16);  // 32 MiB
  char*  P     = (char*) alloc(4 * PLANE);
  u16*   bgh   = (u16*)(P);
  u16*   bgl   = (u16*)(P + PLANE);
  u16*   buh   = (u16*)(P + 2 * PLANE);
  u16*   bul   = (u16*)(P + 3 * PLANE);
  u16*   bdh   = bgh;                    // alias: written after gateup
  u16*   bdl   = bgl;
  float* downb = (float*)(P + 2 * PLANE);  // alias buh: written during down
  u16*   midh  = (u16*)  alloc((size_t)E * T * I * sizeof(u16));
  u16*   midl  = (u16*)  alloc((size_t)E * T * I * sizeof(u16));
  (void)ws_size;

  hipMemsetAsync(cnt, 0, E * sizeof(int), stream);

  prep_x_kernel<<<(T * H / 4) / 256, 256, 0, stream>>>(x, xh, xl);
  prep_gu_kernel<<<dim3(1024, 16), 256, 0, stream>>>(
      wg, wu, bgh, bgl, buh, bul);
  router_kernel<<<T, 256, 0, stream>>>(x, rw, bias, cnt, list, wk4, zerow);

  gateup_kernel<<<2048, 256, 0, stream>>>(
      xh, xl, bgh, bgl, buh, bul, cnt, list, midh, midl);

  prep_d_kernel<<<dim3(1024, 8), 256, 0, stream>>>(wd, bdh, bdl);

  down_kernel<<<4096, 256, 0, stream>>>(
      midh, midl, bdh, bdl, cnt, list, downb);
  combine_kernel<<<(T * H / 4) / 256, 256, 0, stream>>>(
      x, downb, wk4, zerow, out);
}